// Round 1
// baseline (2024.102 us; speedup 1.0000x reference)
//
#include <hip/hip_runtime.h>
#include <hip/hip_bf16.h>

#define DT 0.01f

// sin(x) with Cody-Waite reduction mod pi, accurate to ~2e-7 for |x| < ~6000.
__device__ __forceinline__ float fast_sin(float x) {
  const float INVPI = 0.3183098861837907f;
  float n = rintf(x * INVPI);
  int ni = (int)n;
  float r = fmaf(n, -3.140625f, x);          // n*3.140625 exact for |n| < 2^12
  r = fmaf(n, -9.6765358979e-4f, r);         // pi - 3.140625
  float s = r * r;
  float p = fmaf(s, -2.5052108e-8f, 2.7557319e-6f);
  p = fmaf(s, p, -1.9841270e-4f);
  p = fmaf(s, p, 8.3333333e-3f);
  p = fmaf(s, p, -1.6666667e-1f);
  float res = fmaf(r * s, p, r);             // sin(r), |r| <= pi/2
  return (ni & 1) ? -res : res;              // sin(x) = (-1)^n sin(r)
}

// K0s[h,j] = sum_m k0[h,m,j]   (k0: [128,512,512])
__global__ __launch_bounds__(256) void kPrep1(const float* __restrict__ k0,
                                              float* __restrict__ K0s) {
  int t = blockIdx.x * 256 + threadIdx.x;     // 65536 threads
  int h = t >> 9, j = t & 511;
  const float* p = k0 + (size_t)h * 262144 + j;
  float s = 0.f;
  for (int m = 0; m < 512; ++m) s += p[(size_t)m * 512];
  K0s[t] = s;
}

// K1s[h,j] = sum_m k1[h,m,j]   (k1: [128,512,128])
__global__ __launch_bounds__(256) void kPrep2(const float* __restrict__ k1,
                                              float* __restrict__ K1s) {
  int t = blockIdx.x * 256 + threadIdx.x;     // 16384 threads
  int h = t >> 7, j = t & 127;
  const float* p = k1 + (size_t)h * 65536 + j;
  float s = 0.f;
  for (int m = 0; m < 512; ++m) s += p[(size_t)m * 128];
  K1s[t] = s;
}

// M[l,j] = sum_h K1s[l,h] * K0s[h,j]   ([128,512] = K1s @ K0s)
__global__ __launch_bounds__(256) void kPrep3(const float* __restrict__ K0s,
                                              const float* __restrict__ K1s,
                                              float* __restrict__ M) {
  int t = blockIdx.x * 256 + threadIdx.x;     // 65536 threads
  int l = t >> 9, j = t & 511;
  float s = 0.f;
#pragma unroll 8
  for (int h = 0; h < 128; ++h) s = fmaf(K1s[l * 128 + h], K0s[h * 512 + j], s);
  M[t] = s;
}

// Kernel A: RK4 bookkeeping + s2 = M * y_stage.
// Grid 64 WGs x 256: WG = (b = blk>>2, quarter q = blk&3).
// stage: 0 = init (y = y0), 1..4 = RK stages. y ping-pongs on step parity.
__global__ __launch_bounds__(256) void kA(
    const float* __restrict__ y0, const float* __restrict__ bias,
    const float* __restrict__ M, const float* __restrict__ aggp,
    float* __restrict__ ybuf,    // [2][16][512]
    float* __restrict__ racc,    // [16][512]
    float* __restrict__ s2,      // [16][128]
    float* __restrict__ out,     // [8][16][512]
    int stage, int step) {
  __shared__ float ystage[512];
  __shared__ float red[256];
  const int b = blockIdx.x >> 2, q = blockIdx.x & 3, t = threadIdx.x;
  const float* ycur = ybuf + (step & 1) * 8192;
  float* ynext = ybuf + ((step + 1) & 1) * 8192;

  for (int i = t; i < 512; i += 256) {
    const int idx = b * 512 + i;
    const bool own = (i >> 7) == q;   // this WG owns chunk q of row b
    float ys;
    if (stage == 0) {
      ys = y0[idx];
      if (own) ynext[idx] = ys;       // init writes ybuf[0] (step = -1)
    } else {
      const float r = bias[idx] - (aggp[idx] + aggp[8192 + idx]);
      const float yb = ycur[idx];
      if (stage == 1) {
        ys = fmaf(0.5f * DT, r, yb);
        if (own) racc[idx] = r;
      } else if (stage == 2) {
        ys = fmaf(0.5f * DT, r, yb);
        if (own) racc[idx] = racc[idx] + 2.f * r;
      } else if (stage == 3) {
        ys = fmaf(DT, r, yb);
        if (own) racc[idx] = racc[idx] + 2.f * r;
      } else {  // stage 4: finish step
        ys = yb + (DT / 6.f) * (racc[idx] + r);
        if (own) { ynext[idx] = ys; out[step * 8192 + idx] = ys; }
      }
    }
    ystage[i] = ys;
  }
  __syncthreads();

  // s2[b, l] for l in [q*32, q*32+32): 8 threads per dot, 64 j each.
  const int l = q * 32 + (t >> 3), seg = t & 7;
  const float* Mrow = M + l * 512 + seg * 64;
  float p = 0.f;
#pragma unroll 8
  for (int i = 0; i < 64; ++i) p = fmaf(Mrow[i], ystage[seg * 64 + i], p);
  red[t] = p;
  __syncthreads();
  if (seg == 0) {
    float ssum = 0.f;
#pragma unroll
    for (int k = 0; k < 8; ++k) ssum += red[t + k];
    s2[b * 128 + l] = ssum;
  }
}

// Kernel B: agg partials. One thread per k2 row (l,m); 16 batch accumulators
// in registers; s2 read via wave-uniform (scalar) loads.
// Grid 1024 WGs x 256 threads; each WG covers 256 rows of one l.
__global__ __launch_bounds__(256) void kB(
    const float* __restrict__ k2, const float* __restrict__ adj,
    const float* __restrict__ s2, float* __restrict__ aggp) {
  __shared__ float part[64];
  const int rid = blockIdx.x * 256 + threadIdx.x;  // 0..262143
  const int l = rid >> 9;
  const int half = blockIdx.x & 1;
  const float* __restrict__ row = k2 + (size_t)rid * 128;

  float dot[16];
#pragma unroll
  for (int b = 0; b < 16; ++b) dot[b] = 0.f;

#pragma unroll 2
  for (int jc = 0; jc < 128; jc += 4) {
    const float4 kv = *(const float4*)(row + jc);
#pragma unroll
    for (int b = 0; b < 16; ++b) {
      const float4 sv = *(const float4*)(s2 + b * 128 + jc);  // uniform -> s_load
      dot[b] = fmaf(kv.x, sv.x, dot[b]);
      dot[b] = fmaf(kv.y, sv.y, dot[b]);
      dot[b] = fmaf(kv.z, sv.z, dot[b]);
      dot[b] = fmaf(kv.w, sv.w, dot[b]);
    }
  }

#pragma unroll
  for (int b = 0; b < 16; ++b) {
    float v = adj[(size_t)b * 262144 + rid] * fast_sin(dot[b]);
#pragma unroll
    for (int off = 32; off > 0; off >>= 1) v += __shfl_down(v, off, 64);
    if ((threadIdx.x & 63) == 0) part[(threadIdx.x >> 6) * 16 + b] = v;
  }
  __syncthreads();
  if (threadIdx.x < 16) {
    float ssum = part[threadIdx.x] + part[16 + threadIdx.x] +
                 part[32 + threadIdx.x] + part[48 + threadIdx.x];
    // aggp[half][b][l]
    aggp[half * 8192 + threadIdx.x * 512 + l] = ssum;
  }
}

extern "C" void kernel_launch(void* const* d_in, const int* in_sizes, int n_in,
                              void* d_out, int out_size, void* d_ws, size_t ws_size,
                              hipStream_t stream) {
  const float* y0   = (const float*)d_in[0];  // [16,512]
  const float* bias = (const float*)d_in[1];  // [16,512,1]
  const float* adj  = (const float*)d_in[2];  // [16,512,512]
  const float* k0   = (const float*)d_in[3];  // [128,512,512]
  const float* k1   = (const float*)d_in[4];  // [128,512,128]
  const float* k2   = (const float*)d_in[5];  // [512,512,128]
  float* out = (float*)d_out;                 // [8,16,512] f32

  float* w    = (float*)d_ws;
  float* K0s  = w;               // 65536 floats
  float* K1s  = w + 65536;       // 16384
  float* M    = w + 81920;       // 65536
  float* s2   = w + 147456;      // 2048
  float* ybuf = w + 149504;      // 16384 (2 x 8192, ping-pong)
  float* racc = w + 165888;      // 8192
  float* aggp = w + 174080;      // 16384 (2 halves x [16][512])
  // total: 190464 floats = 762 KB of d_ws

  kPrep1<<<256, 256, 0, stream>>>(k0, K0s);
  kPrep2<<<64, 256, 0, stream>>>(k1, K1s);
  kPrep3<<<256, 256, 0, stream>>>(K0s, K1s, M);

  // init: y = y0, s2 = M*y0  (step = -1 makes ping-pong write ybuf[0])
  kA<<<64, 256, 0, stream>>>(y0, bias, M, aggp, ybuf, racc, s2, out, 0, -1);

  for (int step = 0; step < 8; ++step) {
    for (int stage = 1; stage <= 4; ++stage) {
      kB<<<1024, 256, 0, stream>>>(k2, adj, s2, aggp);
      kA<<<64, 256, 0, stream>>>(y0, bias, M, aggp, ybuf, racc, s2, out, stage, step);
    }
  }
}